// Round 2
// baseline (480.694 us; speedup 1.0000x reference)
//
#include <hip/hip_runtime.h>
#include <hip/hip_bf16.h>
#include <math.h>

#define B 32
#define N 8400
#define M 60
#define C 80
#define KMAX 13
#define INF_COST 1e8f

// ---------- shared math: MUST be bit-identical across kernels ----------
__device__ __forceinline__ float iou_fn(
    float px1, float py1, float px2, float py2,
    float gx1, float gy1, float gx2, float gy2)
{
#pragma clang fp contract(off)
    float ltx = fmaxf(px1, gx1), lty = fmaxf(py1, gy1);
    float rbx = fminf(px2, gx2), rby = fminf(py2, gy2);
    float wx = fmaxf(rbx - ltx, 0.0f), wy = fmaxf(rby - lty, 0.0f);
    float inter = wx * wy;
    float a1 = (px2 - px1) * (py2 - py1);
    float a2 = (gx2 - gx1) * (gy2 - gy1);
    float uni = fmaxf(a1 + a2 - inter, 1e-6f);
    return inter / uni;
}

__device__ __forceinline__ float cost_fn(
    float iou, float logit,
    float pcx, float pcy, float stride,
    float gcx, float gcy)
{
#pragma clang fp contract(off)
    float dx = pcx - gcx, dy = pcy - gcy;
    float dist = sqrtf(dx * dx + dy * dy) / stride;
    float soft = exp10f(dist - 3.0f);                 // can overflow to +inf (valid per ref)
    float iouc = -logf(iou + 1e-7f) * 3.0f;
    float sig = 1.0f / (1.0f + expf(-logit));
    float scale = iou - sig;
    float sc2 = scale * scale;
    float bce = fmaxf(logit, 0.0f) - logit * iou + log1pf(expf(-fabsf(logit)));
    float cls = bce * sc2;
    return (cls + iouc) + soft;
}

// ---------- kernel 1: valid_mask[b,n] ----------
__global__ __launch_bounds__(256) void k_valid(
    const float* __restrict__ priors,
    const float* __restrict__ gt_bboxes,
    const float* __restrict__ pad,
    unsigned char* __restrict__ valid)
{
    int idx = blockIdx.x * 256 + threadIdx.x;
    if (idx >= B * N) return;
    int b = idx / N, n = idx % N;
    float px = priors[n * 4 + 0];
    float py = priors[n * 4 + 1];
    const float* g = gt_bboxes + (size_t)b * M * 4;
    const float* pf = pad + (size_t)b * M;
    unsigned char v = 0;
    for (int m = 0; m < M; m++) {
        float x1 = g[m * 4 + 0], y1 = g[m * 4 + 1];
        float x2 = g[m * 4 + 2], y2 = g[m * 4 + 3];
        float mn = fminf(fminf(px - x1, py - y1), fminf(x2 - px, y2 - py));
        if (mn > 0.0f && pf[m] > 0.0f) { v = 1; break; }
    }
    valid[idx] = v;
}

// ---------- kernel 2: one wave per (b,m) column, register lists + shuffle pops ----------
__global__ __launch_bounds__(64) void k_select(
    const float* __restrict__ pred_bboxes,
    const float* __restrict__ pred_scores,
    const float* __restrict__ priors,
    const int*   __restrict__ gt_labels,
    const float* __restrict__ gt_bboxes,
    const unsigned char* __restrict__ valid,
    float* __restrict__ cK, int* __restrict__ nK)
{
    const int bm = blockIdx.x;
    const int b = bm / M;
    const int tid = threadIdx.x;

    const float4 g = ((const float4*)gt_bboxes)[bm];
    const float gx1 = g.x, gy1 = g.y, gx2 = g.z, gy2 = g.w;
    const float gcx = (gx1 + gx2) * 0.5f, gcy = (gy1 + gy2) * 0.5f;
    const int label = gt_labels[bm];

    // per-thread register lists (all indices compile-time after unroll)
    float t13[KMAX];                 // descending iou values
    float bKv[KMAX]; int bKn[KMAX];  // ascending (cost, n) lexicographic
#pragma unroll
    for (int j = 0; j < KMAX; j++) {
        t13[j] = -1.0f;
        bKv[j] = INFINITY; bKn[j] = 0x7fffffff;
    }

    const float4* pb4 = (const float4*)(pred_bboxes + (size_t)b * N * 4);
    const float4* pr4 = (const float4*)priors;
    const unsigned char* vrow = valid + (size_t)b * N;
    const float* srow = pred_scores + (size_t)b * N * C;

    for (int n = tid; n < N; n += 64) {
        float4 p = pb4[n];
        float iou = iou_fn(p.x, p.y, p.z, p.w, gx1, gy1, gx2, gy2);

        // insert iou into descending top-13 (values only)
        if (iou > t13[KMAX - 1]) {
#pragma unroll
            for (int j = KMAX - 1; j >= 1; --j)
                t13[j] = (t13[j] >= iou) ? t13[j] : (t13[j - 1] >= iou ? iou : t13[j - 1]);
            t13[0] = (t13[0] >= iou) ? t13[0] : iou;
        }

        float c;
        if (vrow[n]) {
            float logit = srow[(size_t)n * C + label];
            float4 pr = pr4[n];
            c = cost_fn(iou, logit, pr.x, pr.y, pr.z, gcx, gcy);
        } else {
            c = INF_COST;
        }

        // insert (c, n) into ascending lexicographic bottom-13
        bool rej = (bKv[KMAX - 1] < c) || (bKv[KMAX - 1] == c && bKn[KMAX - 1] < n);
        if (!rej) {
#pragma unroll
            for (int j = KMAX - 1; j >= 1; --j) {
                bool keep  = (bKv[j] < c)     || (bKv[j] == c     && bKn[j] < n);
                bool pkeep = (bKv[j - 1] < c) || (bKv[j - 1] == c && bKn[j - 1] < n);
                float nv = keep ? bKv[j] : (pkeep ? c : bKv[j - 1]);
                int   nn = keep ? bKn[j] : (pkeep ? n : bKn[j - 1]);
                bKv[j] = nv; bKn[j] = nn;
            }
            bool keep0 = (bKv[0] < c) || (bKv[0] == c && bKn[0] < n);
            if (!keep0) { bKv[0] = c; bKn[0] = n; }
        }
    }

    // ---- phase 1 pops: top-13 sum in descending order (bit-matches top_k().sum()) ----
    float ssum = 0.0f;
#pragma unroll 1
    for (int r = 0; r < KMAX; ++r) {
        float v = t13[0]; int t = tid;
#pragma unroll
        for (int d = 1; d < 64; d <<= 1) {
            float ov = __shfl_xor(v, d);
            int   ot = __shfl_xor(t, d);
            if (ov > v || (ov == v && ot < t)) { v = ov; t = ot; }
        }
        ssum += v;                                   // identical broadcast value on all lanes
        if (tid == t) {
#pragma unroll
            for (int j = 0; j < KMAX - 1; ++j) t13[j] = t13[j + 1];
            t13[KMAX - 1] = -1.0f;
        }
    }
    int K = (int)ssum;                               // trunc == astype(int32)
    if (K < 1) K = 1;

    // ---- phase 2 pops: K-th smallest (cost, n) pair ----
    float ck = 0.0f; int nk = 0;
#pragma unroll 1
    for (int r = 0; r < K; ++r) {
        float v = bKv[0]; int n = bKn[0];
#pragma unroll
        for (int d = 1; d < 64; d <<= 1) {
            float ov = __shfl_xor(v, d);
            int   on = __shfl_xor(n, d);
            if (ov < v || (ov == v && on < n)) { v = ov; n = on; }
        }
        ck = v; nk = n;
        if (tid == (n & 63)) {                       // n ≡ owner lane (mod 64)
#pragma unroll
            for (int j = 0; j < KMAX - 1; ++j) { bKv[j] = bKv[j + 1]; bKn[j] = bKn[j + 1]; }
            bKv[KMAX - 1] = INFINITY; bKn[KMAX - 1] = 0x7fffffff;
        }
    }
    if (tid == 0) { cK[bm] = ck; nK[bm] = nk; }
}

// ---------- kernel 3: per-(b,n) row: matching + outputs ----------
__global__ __launch_bounds__(256) void k_assign(
    const float* __restrict__ pred_bboxes,
    const float* __restrict__ pred_scores,
    const float* __restrict__ priors,
    const int*   __restrict__ gt_labels,
    const float* __restrict__ gt_bboxes,
    const float* __restrict__ pad,
    const unsigned char* __restrict__ valid,
    const float* __restrict__ cK,
    const int*   __restrict__ nK,
    float* __restrict__ out)
{
    __shared__ float s_box[M][4];
    __shared__ float s_gc[M][2];
    __shared__ float s_ck[M];
    __shared__ int   s_lab[M];
    __shared__ int   s_nk[M];
    __shared__ unsigned char s_gtv[M];

    const int b = blockIdx.y;
    const int n = blockIdx.x * 256 + threadIdx.x;

    if (threadIdx.x < M) {
        int m = threadIdx.x, gi = b * M + m;
        float4 g = ((const float4*)gt_bboxes)[gi];
        s_box[m][0] = g.x; s_box[m][1] = g.y; s_box[m][2] = g.z; s_box[m][3] = g.w;
        s_gc[m][0] = (g.x + g.z) * 0.5f;
        s_gc[m][1] = (g.y + g.w) * 0.5f;
        s_ck[m] = cK[gi];
        s_lab[m] = gt_labels[gi];
        s_nk[m] = nK[gi];
        s_gtv[m] = (pad[gi] > 0.0f) ? 1 : 0;
    }
    __syncthreads();
    if (n >= N) return;

    const size_t idx = (size_t)b * N + n;
    const float4 p = ((const float4*)pred_bboxes)[idx];
    const float4 pr = ((const float4*)priors)[n];
    const int vn = valid[idx];
    const float* scores = pred_scores + idx * C;

    int count = 0, firstm = -1;
    float firstiou = 0.0f;
    float minc = INFINITY; int amin = 0; float aminiou = 0.0f;

    for (int m = 0; m < M; m++) {
        float iou = iou_fn(p.x, p.y, p.z, p.w,
                           s_box[m][0], s_box[m][1], s_box[m][2], s_box[m][3]);
        float c;
        if (vn) {
            float logit = scores[s_lab[m]];
            c = cost_fn(iou, logit, pr.x, pr.y, pr.z, s_gc[m][0], s_gc[m][1]);
        } else {
            c = INF_COST;
        }

        if (c < minc) { minc = c; amin = m; aminiou = iou; }  // first-min, like jnp.argmin

        float ckm = s_ck[m]; int nkm = s_nk[m];
        bool matched = s_gtv[m] && (c < ckm || (c == ckm && n <= nkm));
        if (matched) { count++; if (firstm < 0) { firstm = m; firstiou = iou; } }
    }

    int mstar; float mi;
    if (count > 1)       { mstar = amin;   mi = aminiou; }
    else if (count == 1) { mstar = firstm; mi = firstiou; }
    else                 { mstar = -1;     mi = 0.0f; }

    float* o_lab = out;
    float* o_w   = out + (size_t)B * N;
    float* o_box = out + (size_t)2 * B * N;
    float* o_met = out + (size_t)6 * B * N;

    o_w[idx] = 1.0f;
    if (mstar >= 0) {
        o_lab[idx] = (float)s_lab[mstar];
        o_box[idx * 4 + 0] = s_box[mstar][0];
        o_box[idx * 4 + 1] = s_box[mstar][1];
        o_box[idx * 4 + 2] = s_box[mstar][2];
        o_box[idx * 4 + 3] = s_box[mstar][3];
        o_met[idx] = mi;
    } else {
        o_lab[idx] = (float)C;
        o_box[idx * 4 + 0] = 0.0f;
        o_box[idx * 4 + 1] = 0.0f;
        o_box[idx * 4 + 2] = 0.0f;
        o_box[idx * 4 + 3] = 0.0f;
        o_met[idx] = 0.0f;
    }
}

extern "C" void kernel_launch(void* const* d_in, const int* in_sizes, int n_in,
                              void* d_out, int out_size, void* d_ws, size_t ws_size,
                              hipStream_t stream) {
    const float* pred_bboxes = (const float*)d_in[0];
    const float* pred_scores = (const float*)d_in[1];
    const float* priors      = (const float*)d_in[2];
    const int*   gt_labels   = (const int*)d_in[3];
    const float* gt_bboxes   = (const float*)d_in[4];
    const float* pad         = (const float*)d_in[5];

    unsigned char* ws = (unsigned char*)d_ws;
    unsigned char* valid = ws;                                   // B*N bytes
    float* cKp = (float*)(ws + (size_t)B * N);                   // B*M floats
    int*   nKp = (int*)(ws + (size_t)B * N + (size_t)B * M * 4); // B*M ints

    float* out = (float*)d_out;

    k_valid <<<(B * N + 255) / 256, 256, 0, stream>>>(priors, gt_bboxes, pad, valid);
    k_select<<<B * M, 64, 0, stream>>>(pred_bboxes, pred_scores, priors, gt_labels,
                                       gt_bboxes, valid, cKp, nKp);
    k_assign<<<dim3((N + 255) / 256, B), 256, 0, stream>>>(pred_bboxes, pred_scores, priors,
                                                           gt_labels, gt_bboxes, pad, valid,
                                                           cKp, nKp, out);
}

// Round 3
// 341.631 us; speedup vs baseline: 1.4071x; 1.4071x over previous
//
#include <hip/hip_runtime.h>
#include <hip/hip_bf16.h>
#include <math.h>

#define B 32
#define N 8400
#define M 60
#define C 80
#define KMAX 13
#define INF_COST 1e8f

// ---------- shared math: MUST be bit-identical across kernels ----------
__device__ __forceinline__ float iou_fn(
    float px1, float py1, float px2, float py2,
    float gx1, float gy1, float gx2, float gy2)
{
#pragma clang fp contract(off)
    float ltx = fmaxf(px1, gx1), lty = fmaxf(py1, gy1);
    float rbx = fminf(px2, gx2), rby = fminf(py2, gy2);
    float wx = fmaxf(rbx - ltx, 0.0f), wy = fmaxf(rby - lty, 0.0f);
    float inter = wx * wy;
    float a1 = (px2 - px1) * (py2 - py1);
    float a2 = (gx2 - gx1) * (gy2 - gy1);
    float uni = fmaxf(a1 + a2 - inter, 1e-6f);
    return inter / uni;
}

__device__ __forceinline__ float cost_fn(
    float iou, float logit,
    float pcx, float pcy, float stride,
    float gcx, float gcy)
{
#pragma clang fp contract(off)
    float dx = pcx - gcx, dy = pcy - gcy;
    float dist = sqrtf(dx * dx + dy * dy) / stride;
    float soft = exp10f(dist - 3.0f);                 // can overflow to +inf (valid per ref)
    float iouc = -logf(iou + 1e-7f) * 3.0f;
    float sig = 1.0f / (1.0f + expf(-logit));
    float scale = iou - sig;
    float sc2 = scale * scale;
    float bce = fmaxf(logit, 0.0f) - logit * iou + log1pf(expf(-fabsf(logit)));
    float cls = bce * sc2;
    return (cls + iouc) + soft;
}

// ---------- kernel 1: valid_mask[b,n] ----------
__global__ __launch_bounds__(256) void k_valid(
    const float* __restrict__ priors,
    const float* __restrict__ gt_bboxes,
    const float* __restrict__ pad,
    unsigned char* __restrict__ valid)
{
    int idx = blockIdx.x * 256 + threadIdx.x;
    if (idx >= B * N) return;
    int b = idx / N, n = idx % N;
    float px = priors[n * 4 + 0];
    float py = priors[n * 4 + 1];
    const float* g = gt_bboxes + (size_t)b * M * 4;
    const float* pf = pad + (size_t)b * M;
    unsigned char v = 0;
    for (int m = 0; m < M; m++) {
        float x1 = g[m * 4 + 0], y1 = g[m * 4 + 1];
        float x2 = g[m * 4 + 2], y2 = g[m * 4 + 3];
        float mn = fminf(fminf(px - x1, py - y1), fminf(x2 - px, y2 - py));
        if (mn > 0.0f && pf[m] > 0.0f) { v = 1; break; }
    }
    valid[idx] = v;
}

// ---------- kernel 1b: per-m score columns, coalesced: t[b][m][n] = scores[b][n][lab[b][m]] ----------
// grid 4224 = 8 XCD * 528 ; 132 tiles (of 64 n) per b, 4 b per XCD group
__global__ __launch_bounds__(256) void k_transpose(
    const float* __restrict__ scores,
    const int*   __restrict__ labels,
    float* __restrict__ t)
{
    __shared__ float s_t[80][65];     // 20.8 KB, padded
    __shared__ int s_lab[M];

    const int i = blockIdx.x;
    const int cidx = (i & 7) * 528 + (i >> 3);
    const int b = cidx / 132;
    const int tile = cidx % 132;
    const int n0 = tile * 64;
    const int lim = (N - n0 < 64) ? (N - n0) : 64;   // 64 or 16

    if (threadIdx.x < M) s_lab[threadIdx.x] = labels[b * M + threadIdx.x];

    const float4* src4 = (const float4*)(scores + ((size_t)b * N + n0) * C);
    for (int idx = threadIdx.x; idx < lim * 20; idx += 256) {
        int r = idx / 20, q = idx % 20;
        float4 v = src4[r * 20 + q];
        s_t[4 * q + 0][r] = v.x;
        s_t[4 * q + 1][r] = v.y;
        s_t[4 * q + 2][r] = v.z;
        s_t[4 * q + 3][r] = v.w;
    }
    __syncthreads();

    for (int idx = threadIdx.x; idx < M * 16; idx += 256) {
        int m = idx >> 4, q = idx & 15;
        if (4 * q < lim) {
            int lab = s_lab[m];
            float4 v = make_float4(s_t[lab][4 * q + 0], s_t[lab][4 * q + 1],
                                   s_t[lab][4 * q + 2], s_t[lab][4 * q + 3]);
            *(float4*)(t + ((size_t)b * M + m) * N + n0 + 4 * q) = v;
        }
    }
}

// ---------- kernel 2: one 256-thread block per (b,m) column; LDS scan + butterfly pops ----------
// grid 1920 = 8 XCD * 240 (b-major grouping per XCD)
__global__ __launch_bounds__(256) void k_select(
    const float* __restrict__ pred_bboxes,
    const float* __restrict__ pred_scores,
    const float* __restrict__ tsc,
    const float* __restrict__ priors,
    const int*   __restrict__ gt_labels,
    const float* __restrict__ gt_bboxes,
    const float* __restrict__ pad,
    const unsigned char* __restrict__ valid,
    float* __restrict__ cK, int* __restrict__ nK,
    int use_t)
{
    __shared__ float s_val[N];        // 33.6 KB
    __shared__ float s_wv[4];
    __shared__ int   s_wi[4];
    __shared__ int   s_K;

    const int i = blockIdx.x;
    const int bm = (i & 7) * 240 + (i >> 3);
    if (pad[bm] == 0.0f) return;      // padded GT column: cK/nK never consumed

    const int b = bm / M;
    const int tid = threadIdx.x;
    const int lane = tid & 63;
    const int wid = tid >> 6;

    const float4 g = ((const float4*)gt_bboxes)[bm];
    const float gx1 = g.x, gy1 = g.y, gx2 = g.z, gy2 = g.w;
    const float4* pb4 = ((const float4*)pred_bboxes) + (size_t)b * N;

    // ---- phase 1 fill: iou column ----
    for (int n = tid; n < N; n += 256) {
        float4 p = pb4[n];
        s_val[n] = iou_fn(p.x, p.y, p.z, p.w, gx1, gy1, gx2, gy2);
    }
    __syncthreads();

    // ---- 13 pops, descending sum (bit-matches top_k().sum()) ----
    float ssum = 0.0f;
    for (int r = 0; r < KMAX; ++r) {
        float bv = -1.0f; int bi = 0x7fffffff;
        for (int n = tid; n < N; n += 256) {
            float v = s_val[n];
            if (v > bv) { bv = v; bi = n; }       // ascending n: first on tie
        }
#pragma unroll
        for (int d = 1; d < 64; d <<= 1) {
            float ov = __shfl_xor(bv, d);
            int   oi = __shfl_xor(bi, d);
            if (ov > bv || (ov == bv && oi < bi)) { bv = ov; bi = oi; }
        }
        if (lane == 0) { s_wv[wid] = bv; s_wi[wid] = bi; }
        __syncthreads();
        if (tid == 0) {
#pragma unroll
            for (int w = 1; w < 4; ++w) {
                float v = s_wv[w]; int ix = s_wi[w];
                if (v > bv || (v == bv && ix < bi)) { bv = v; bi = ix; }
            }
            ssum += bv;
            s_val[bi] = -2.0f;                    // excluded: below any real iou
        }
        __syncthreads();
    }
    if (tid == 0) {
        int K = (int)ssum;                        // trunc == astype(int32)
        s_K = (K < 1) ? 1 : K;
    }

    // ---- phase 2 fill: cost column ----
    const float gcx = (gx1 + gx2) * 0.5f, gcy = (gy1 + gy2) * 0.5f;
    const int label = gt_labels[bm];
    const float* tcol = tsc + (size_t)bm * N;     // deref only if use_t
    const float* srow = pred_scores + (size_t)b * N * C;
    const unsigned char* vrow = valid + (size_t)b * N;
    const float4* pr4 = (const float4*)priors;

    for (int n = tid; n < N; n += 256) {
        float c;
        if (vrow[n]) {
            float4 p = pb4[n];
            float iou = iou_fn(p.x, p.y, p.z, p.w, gx1, gy1, gx2, gy2);
            float logit = use_t ? tcol[n] : srow[(size_t)n * C + label];
            float4 pr = pr4[n];
            c = cost_fn(iou, logit, pr.x, pr.y, pr.z, gcx, gcy);
        } else {
            c = INF_COST;
        }
        s_val[n] = c;
    }
    __syncthreads();

    // ---- K pops: K-th smallest (cost, n) lex pair ----
    const int K = s_K;
    float ck = 0.0f; int nk = 0;
    for (int r = 0; r < K; ++r) {
        float bv = INFINITY; int bi = 0x7fffffff;
        for (int n = tid; n < N; n += 256) {
            float v = s_val[n];
            // NaN markers fail both; real +inf beats (inf, 0x7fffffff) sentinel by index
            if (v < bv || (v == bv && n < bi)) { bv = v; bi = n; }
        }
#pragma unroll
        for (int d = 1; d < 64; d <<= 1) {
            float ov = __shfl_xor(bv, d);
            int   oi = __shfl_xor(bi, d);
            if (ov < bv || (ov == bv && oi < bi)) { bv = ov; bi = oi; }
        }
        if (lane == 0) { s_wv[wid] = bv; s_wi[wid] = bi; }
        __syncthreads();
        if (tid == 0) {
#pragma unroll
            for (int w = 1; w < 4; ++w) {
                float v = s_wv[w]; int ix = s_wi[w];
                if (v < bv || (v == bv && ix < bi)) { bv = v; bi = ix; }
            }
            ck = bv; nk = bi;
            s_val[bi] = __int_as_float(0x7fc00000);   // NaN: never re-selected
        }
        __syncthreads();
    }
    if (tid == 0) { cK[bm] = ck; nK[bm] = nk; }
}

// ---------- kernel 3: per-(b,n) row: matching + outputs ----------
// grid 1056 = 8 XCD * 132 ; 33 chunks per b, 4 b per XCD group
__global__ __launch_bounds__(256) void k_assign(
    const float* __restrict__ pred_bboxes,
    const float* __restrict__ pred_scores,
    const float* __restrict__ tsc,
    const float* __restrict__ priors,
    const int*   __restrict__ gt_labels,
    const float* __restrict__ gt_bboxes,
    const float* __restrict__ pad,
    const unsigned char* __restrict__ valid,
    const float* __restrict__ cK,
    const int*   __restrict__ nK,
    float* __restrict__ out,
    int use_t)
{
    __shared__ float s_box[M][4];
    __shared__ float s_gc[M][2];
    __shared__ float s_ck[M];
    __shared__ int   s_lab[M];
    __shared__ int   s_nk[M];
    __shared__ unsigned char s_gtv[M];

    const int i = blockIdx.x;
    const int cidx = (i & 7) * 132 + (i >> 3);
    const int b = cidx / 33;
    const int chunk = cidx % 33;
    const int n = chunk * 256 + threadIdx.x;

    if (threadIdx.x < M) {
        int m = threadIdx.x, gi = b * M + m;
        float4 g = ((const float4*)gt_bboxes)[gi];
        s_box[m][0] = g.x; s_box[m][1] = g.y; s_box[m][2] = g.z; s_box[m][3] = g.w;
        s_gc[m][0] = (g.x + g.z) * 0.5f;
        s_gc[m][1] = (g.y + g.w) * 0.5f;
        s_ck[m] = cK[gi];
        s_lab[m] = gt_labels[gi];
        s_nk[m] = nK[gi];
        s_gtv[m] = (pad[gi] > 0.0f) ? 1 : 0;
    }
    __syncthreads();
    if (n >= N) return;

    const size_t idx = (size_t)b * N + n;
    const float4 p = ((const float4*)pred_bboxes)[idx];
    const float4 pr = ((const float4*)priors)[n];
    const int vn = valid[idx];
    const float* scores = pred_scores + idx * C;
    const float* tb = tsc + (size_t)b * M * N;    // deref only if use_t

    int count = 0, firstm = -1;
    float firstiou = 0.0f;
    float minc = INFINITY; int amin = 0; float aminiou = 0.0f;

    for (int m = 0; m < M; m++) {
        float iou = iou_fn(p.x, p.y, p.z, p.w,
                           s_box[m][0], s_box[m][1], s_box[m][2], s_box[m][3]);
        float c;
        if (vn) {
            float logit = use_t ? tb[(size_t)m * N + n] : scores[s_lab[m]];
            c = cost_fn(iou, logit, pr.x, pr.y, pr.z, s_gc[m][0], s_gc[m][1]);
        } else {
            c = INF_COST;
        }

        if (c < minc) { minc = c; amin = m; aminiou = iou; }  // first-min, like jnp.argmin

        float ckm = s_ck[m]; int nkm = s_nk[m];
        bool matched = s_gtv[m] && (c < ckm || (c == ckm && n <= nkm));
        if (matched) { count++; if (firstm < 0) { firstm = m; firstiou = iou; } }
    }

    int mstar; float mi;
    if (count > 1)       { mstar = amin;   mi = aminiou; }
    else if (count == 1) { mstar = firstm; mi = firstiou; }
    else                 { mstar = -1;     mi = 0.0f; }

    float* o_lab = out;
    float* o_w   = out + (size_t)B * N;
    float* o_box = out + (size_t)2 * B * N;
    float* o_met = out + (size_t)6 * B * N;

    o_w[idx] = 1.0f;
    if (mstar >= 0) {
        o_lab[idx] = (float)s_lab[mstar];
        o_box[idx * 4 + 0] = s_box[mstar][0];
        o_box[idx * 4 + 1] = s_box[mstar][1];
        o_box[idx * 4 + 2] = s_box[mstar][2];
        o_box[idx * 4 + 3] = s_box[mstar][3];
        o_met[idx] = mi;
    } else {
        o_lab[idx] = (float)C;
        o_box[idx * 4 + 0] = 0.0f;
        o_box[idx * 4 + 1] = 0.0f;
        o_box[idx * 4 + 2] = 0.0f;
        o_box[idx * 4 + 3] = 0.0f;
        o_met[idx] = 0.0f;
    }
}

extern "C" void kernel_launch(void* const* d_in, const int* in_sizes, int n_in,
                              void* d_out, int out_size, void* d_ws, size_t ws_size,
                              hipStream_t stream) {
    const float* pred_bboxes = (const float*)d_in[0];
    const float* pred_scores = (const float*)d_in[1];
    const float* priors      = (const float*)d_in[2];
    const int*   gt_labels   = (const int*)d_in[3];
    const float* gt_bboxes   = (const float*)d_in[4];
    const float* pad         = (const float*)d_in[5];
    float* out = (float*)d_out;

    const size_t t_bytes = (size_t)B * M * N * sizeof(float);       // 64,512,000
    const size_t need = t_bytes + (size_t)B * N + (size_t)B * M * 8;
    const int use_t = (ws_size >= need) ? 1 : 0;                    // ws_size fixed -> deterministic

    unsigned char* ws = (unsigned char*)d_ws;
    float* tsc; unsigned char* valid; float* cKp; int* nKp;
    if (use_t) {
        tsc   = (float*)ws;
        valid = ws + t_bytes;
        cKp   = (float*)(ws + t_bytes + (size_t)B * N);
        nKp   = (int*)  (ws + t_bytes + (size_t)B * N + (size_t)B * M * 4);
    } else {
        tsc   = (float*)ws;   // never dereferenced
        valid = ws;
        cKp   = (float*)(ws + (size_t)B * N);
        nKp   = (int*)  (ws + (size_t)B * N + (size_t)B * M * 4);
    }

    k_valid<<<(B * N + 255) / 256, 256, 0, stream>>>(priors, gt_bboxes, pad, valid);
    if (use_t)
        k_transpose<<<B * 132, 256, 0, stream>>>(pred_scores, gt_labels, tsc);
    k_select<<<B * M, 256, 0, stream>>>(pred_bboxes, pred_scores, tsc, priors, gt_labels,
                                        gt_bboxes, pad, valid, cKp, nKp, use_t);
    k_assign<<<33 * B, 256, 0, stream>>>(pred_bboxes, pred_scores, tsc, priors, gt_labels,
                                         gt_bboxes, pad, valid, cKp, nKp, out, use_t);
}